// Round 2
// baseline (228.640 us; speedup 1.0000x reference)
//
#include <hip/hip_runtime.h>
#include <stdint.h>

#define AS1 __attribute__((address_space(1)))
#define AS3 __attribute__((address_space(3)))

typedef __bf16 bf16x8 __attribute__((ext_vector_type(8)));
typedef float f32x4 __attribute__((ext_vector_type(4)));

constexpr int NB = 8;     // batches
constexpr int N  = 2048;  // nodes
constexpr int F  = 128;   // features (in == out)

__device__ __forceinline__ unsigned short bf16r(float f) {
    unsigned u = __float_as_uint(f);
    return (unsigned short)((u + 0x7FFFu + ((u >> 16) & 1u)) >> 16);
}
__device__ __forceinline__ float bf2f(unsigned short s) {
    return __uint_as_float(((unsigned)s) << 16);
}

// ---------------------------------------------------------------------------
// Wb2 element layout (MFMA-B-operand native, linear in k-chunks):
//   byte(b, n, o) = b*N*F*2 + (n>>3)*2048 + o*16 + (n&7)*2
// BK=32 chunk c = contiguous 8192 B at b*N*F*2 + c*8192.
// ---------------------------------------------------------------------------

// K1 (fused): Wh = h @ W^T;  e = Wh @ a2;  p = exp(e);
//   p16 = bf16(p);  Wb2 = bf16(bf2f(p16) * Wh)        [unchanged, proven]
__global__ __launch_bounds__(256) void k1_wh(const float* __restrict__ h,
                                             const float* __restrict__ W,
                                             const float* __restrict__ a,
                                             unsigned short* __restrict__ Wb2,
                                             unsigned short* __restrict__ p16) {
    __shared__ float epart[2][64];

    const int tid  = threadIdx.x;
    const int lane = tid & 63, wid = tid >> 6;
    const int quad = lane >> 4, l15 = lane & 15;
    const int wm = wid >> 1, wn = wid & 1;
    const int m0 = blockIdx.x * 64;
    const int batch = m0 >> 11;
    const int nbase = m0 & 2047;

    f32x4 acc[2][4] = {};

#pragma unroll
    for (int kk = 0; kk < 4; ++kk) {
        const int k = kk * 32 + quad * 8;
        bf16x8 afr[2], bfr[4];
#pragma unroll
        for (int rt = 0; rt < 2; ++rt) {
            const float* src = h + (size_t)(m0 + wm * 32 + rt * 16 + l15) * F + k;
            float4 x0 = *(const float4*)src;
            float4 x1 = *(const float4*)(src + 4);
            afr[rt][0] = (__bf16)x0.x; afr[rt][1] = (__bf16)x0.y;
            afr[rt][2] = (__bf16)x0.z; afr[rt][3] = (__bf16)x0.w;
            afr[rt][4] = (__bf16)x1.x; afr[rt][5] = (__bf16)x1.y;
            afr[rt][6] = (__bf16)x1.z; afr[rt][7] = (__bf16)x1.w;
        }
#pragma unroll
        for (int ct = 0; ct < 4; ++ct) {
            const int o = wn * 64 + ct * 16 + l15;
            const float* src = W + (size_t)o * F + k;
            float4 x0 = *(const float4*)src;
            float4 x1 = *(const float4*)(src + 4);
            bfr[ct][0] = (__bf16)x0.x; bfr[ct][1] = (__bf16)x0.y;
            bfr[ct][2] = (__bf16)x0.z; bfr[ct][3] = (__bf16)x0.w;
            bfr[ct][4] = (__bf16)x1.x; bfr[ct][5] = (__bf16)x1.y;
            bfr[ct][6] = (__bf16)x1.z; bfr[ct][7] = (__bf16)x1.w;
        }
#pragma unroll
        for (int rt = 0; rt < 2; ++rt)
#pragma unroll
            for (int ct = 0; ct < 4; ++ct)
                acc[rt][ct] = __builtin_amdgcn_mfma_f32_16x16x32_bf16(
                    afr[rt], bfr[ct], acc[rt][ct], 0, 0, 0);
    }

    float a2v[4];
#pragma unroll
    for (int ct = 0; ct < 4; ++ct) a2v[ct] = a[F + wn * 64 + ct * 16 + l15];

    float ep[2][4];
#pragma unroll
    for (int rt = 0; rt < 2; ++rt)
#pragma unroll
        for (int g = 0; g < 4; ++g) {
            float s = 0.f;
#pragma unroll
            for (int ct = 0; ct < 4; ++ct) s += acc[rt][ct][g] * a2v[ct];
            ep[rt][g] = s;
        }
#pragma unroll
    for (int m = 1; m < 16; m <<= 1)
#pragma unroll
        for (int rt = 0; rt < 2; ++rt)
#pragma unroll
            for (int g = 0; g < 4; ++g)
                ep[rt][g] += __shfl_xor(ep[rt][g], m);

    if (l15 == 0)
#pragma unroll
        for (int rt = 0; rt < 2; ++rt)
#pragma unroll
            for (int g = 0; g < 4; ++g)
                epart[wn][wm * 32 + rt * 16 + quad * 4 + g] = ep[rt][g];
    __syncthreads();

#pragma unroll
    for (int rt = 0; rt < 2; ++rt)
#pragma unroll
        for (int ct = 0; ct < 4; ++ct) {
            const int o  = wn * 64 + ct * 16 + l15;
            const int r0 = wm * 32 + rt * 16 + quad * 4;
            const int n0 = nbase + r0;
            ushort4 v;
#pragma unroll
            for (int g = 0; g < 4; ++g) {
                const float e  = epart[0][r0 + g] + epart[1][r0 + g];
                const float pf = bf2f(bf16r(expf(e)));
                (&v.x)[g] = bf16r(pf * acc[rt][ct][g]);
            }
            size_t off = (size_t)batch * N * F + (size_t)(n0 >> 3) * 1024 + o * 8 + (n0 & 7);
            *(ushort4*)&Wb2[off] = v;
        }

    if (tid < 64) {
        const float e = epart[0][tid] + epart[1][tid];
        p16[batch * N + nbase + tid] = bf16r(expf(e));
    }
}

// K3' (fused, LDS-free, barrier-free): full-j masked GEMM + denom + divide.
//   out[b][i][o] = (sum_j adj[b][i][j]*Wb2[j][o]) / (sum_j adj[b][i][j]*p[j])
// Grid 512 = (it 0..63)<<3 | b  -> b = blk&7 pins batch->XCD, Wb2 slice
// (512 KB) + p16 (4 KB) L2-resident per XCD. 2 blocks/CU, 8 waves/CU.
// Block = 32 rows; waves 2x2: wm = row-half (16 rows), wn = o-half (64 cols).
// A (adj) loaded straight to registers in MFMA-native layout: a wave's 4
// quads jointly consume each 128-B adj line exactly once -> adj read once
// from HBM, no staging. B fragments read from the L2-resident Wb2 image
// (byte-identical addressing to the old LDS image). One-chunk-deep software
// prefetch; no __syncthreads, no global_load_lds, no vmcnt(0) drains.
// dacc's C/D layout (row = quad*4+g) puts each row's denominator in every
// lane owning that row -> divide in-register, write final f32 out.
__global__ __launch_bounds__(256, 2) void k3_fused(const float* __restrict__ adj,
                                                   const unsigned short* __restrict__ Wb2,
                                                   const unsigned short* __restrict__ p16,
                                                   float* __restrict__ out) {
    const int tid  = threadIdx.x;
    const int lane = tid & 63, wid = tid >> 6;
    const int quad = lane >> 4, l15 = lane & 15;
    const int wm = wid >> 1, wn = wid & 1;
    const int b  = blockIdx.x & 7;
    const int it = blockIdx.x >> 3;        // 0..63
    const int i0 = it * 32;
    const int rowA = i0 + wm * 16 + l15;   // the adj row this lane streams

    const float* aP = adj + (size_t)b * N * N + (size_t)rowA * N + quad * 8;
    const char*  bP = (const char*)Wb2 + (size_t)b * (N * F * 2)
                    + quad * 2048 + wn * 1024 + l15 * 16;
    const char*  pP = (const char*)p16 + (size_t)b * N * 2 + quad * 16;

    f32x4 acc[4] = {};
    f32x4 dacc = {0.f, 0.f, 0.f, 0.f};

    // prefetch chunk 0
    f32x4  a0n = *(const f32x4*)(aP);
    f32x4  a1n = *(const f32x4*)(aP + 4);
    bf16x8 bn0 = *(const bf16x8*)(bP + 0 * 256);
    bf16x8 bn1 = *(const bf16x8*)(bP + 1 * 256);
    bf16x8 bn2 = *(const bf16x8*)(bP + 2 * 256);
    bf16x8 bn3 = *(const bf16x8*)(bP + 3 * 256);
    bf16x8 pn  = *(const bf16x8*)(pP);

#pragma unroll 2
    for (int c = 0; c < 64; ++c) {
        f32x4  a0 = a0n, a1 = a1n;
        bf16x8 b0 = bn0, b1 = bn1, b2 = bn2, b3 = bn3, pv = pn;
        if (c + 1 < 64) {
            const float* aN = aP + (size_t)(c + 1) * 32;
            const char*  bN = bP + (size_t)(c + 1) * 8192;
            a0n = *(const f32x4*)(aN);
            a1n = *(const f32x4*)(aN + 4);
            bn0 = *(const bf16x8*)(bN + 0 * 256);
            bn1 = *(const bf16x8*)(bN + 1 * 256);
            bn2 = *(const bf16x8*)(bN + 2 * 256);
            bn3 = *(const bf16x8*)(bN + 3 * 256);
            pn  = *(const bf16x8*)(pP + (size_t)(c + 1) * 64);
        }
        bf16x8 af;
        af[0] = (__bf16)a0[0]; af[1] = (__bf16)a0[1];
        af[2] = (__bf16)a0[2]; af[3] = (__bf16)a0[3];
        af[4] = (__bf16)a1[0]; af[5] = (__bf16)a1[1];
        af[6] = (__bf16)a1[2]; af[7] = (__bf16)a1[3];

        acc[0] = __builtin_amdgcn_mfma_f32_16x16x32_bf16(af, b0, acc[0], 0, 0, 0);
        acc[1] = __builtin_amdgcn_mfma_f32_16x16x32_bf16(af, b1, acc[1], 0, 0, 0);
        acc[2] = __builtin_amdgcn_mfma_f32_16x16x32_bf16(af, b2, acc[2], 0, 0, 0);
        acc[3] = __builtin_amdgcn_mfma_f32_16x16x32_bf16(af, b3, acc[3], 0, 0, 0);
        dacc   = __builtin_amdgcn_mfma_f32_16x16x32_bf16(af, pv, dacc,   0, 0, 0);
    }

    // Epilogue: divide by per-row denominator (in-lane) and store final f32.
#pragma unroll
    for (int g = 0; g < 4; ++g) {
        const float inv = 1.0f / dacc[g];
        float* orow = out + ((size_t)b * N + i0 + wm * 16 + quad * 4 + g) * F
                    + wn * 64 + l15;
        orow[0]  = acc[0][g] * inv;
        orow[16] = acc[1][g] * inv;
        orow[32] = acc[2][g] * inv;
        orow[48] = acc[3][g] * inv;
    }
}

// ---------------------------------------------------------------------------
extern "C" void kernel_launch(void* const* d_in, const int* in_sizes, int n_in,
                              void* d_out, int out_size, void* d_ws, size_t ws_size,
                              hipStream_t stream) {
    const float* h   = (const float*)d_in[0];
    const float* adj = (const float*)d_in[1];
    const float* W   = (const float*)d_in[2];
    const float* a   = (const float*)d_in[3];
    float* out = (float*)d_out;

    unsigned short* Wb2 = (unsigned short*)d_ws;                        // 4 MB
    unsigned short* p16 = (unsigned short*)((char*)d_ws + (4u << 20));  // 32 KB

    k1_wh<<<NB * N / 64, 256, 0, stream>>>(h, W, a, Wb2, p16);
    k3_fused<<<NB * 64, 256, 0, stream>>>(adj, Wb2, p16, out);
}